// Round 5
// baseline (6199.265 us; speedup 1.0000x reference)
//
#include <hip/hip_runtime.h>
#include <hip/hip_bf16.h>

typedef __attribute__((ext_vector_type(8))) short short8;
typedef __attribute__((ext_vector_type(4))) float floatx4;
typedef __attribute__((ext_vector_type(4))) int intx4;
typedef __attribute__((ext_vector_type(2))) int intx2;

#define T_STEPS 512
#define BATCH   32
#define HDIM    1024
#define GATE4   4096
#define DA_DIM  64
#define PWG     128
#define RING    16
#define AROWS   8
#define EPS_LN  1e-5f

// round-to-nearest-even fp32 -> bf16 bit pattern. Finite input can never
// produce 0xFFFF, so 0xFFFFFFFF dwords are a safe "not yet written" sentinel.
__device__ __forceinline__ unsigned short f2bf(float f) {
    unsigned u = __float_as_uint(f);
    unsigned r = (u + 0x7FFFu + ((u >> 16) & 1u)) >> 16;
    return (unsigned short)r;
}

__device__ __forceinline__ float fast_sigmoid(float x) {
    return __builtin_amdgcn_rcpf(1.f + __expf(-x));
}
__device__ __forceinline__ float fast_tanh(float x) {
    // tanh(x) = 1 - 2/(1+exp(2x)); saturates correctly at +/-inf
    return 1.f - 2.f * __builtin_amdgcn_rcpf(1.f + __expf(2.f * x));
}

// device-coherent ops (to coherence point / IF$)
__device__ __forceinline__ void coh_store8(void* p, intx2 v) {
    asm volatile("global_store_dwordx2 %0, %1, off sc0 sc1" :: "v"(p), "v"(v) : "memory");
}
__device__ __forceinline__ short8 coh_load16(const void* p) {
    short8 v;
    asm volatile("global_load_dwordx4 %0, %1, off sc0 sc1" : "=v"(v) : "v"(p) : "memory");
    return v;
}
__device__ __forceinline__ void waitcnt_vm0() {
    asm volatile("s_waitcnt vmcnt(0)" ::: "memory");
}

// ---------------------------------------------------------------------------
// W fragment prep: wf[w][mt][kb][lane][j]  (A-operand layout, K=[x;h], 2048)
// ---------------------------------------------------------------------------
__global__ void __launch_bounds__(256) prep_wfrag(
    const float* __restrict__ Wih, const float* __restrict__ Whh,
    unsigned short* __restrict__ wf)
{
    int gid  = blockIdx.x * 256 + threadIdx.x;   // 1,048,576
    int lane = gid & 63;
    int kb   = (gid >> 6) & 63;
    int mt   = (gid >> 12) & 1;
    int w    = gid >> 13;                        // 0..127
    int m    = lane & 15;
    int row  = (m >> 2) * HDIM + w * 8 + mt * 4 + (m & 3);
    int k0   = kb * 32 + (lane >> 4) * 8;
    const float* src = (k0 < HDIM) ? (Wih + (size_t)row * HDIM + k0)
                                   : (Whh + (size_t)row * HDIM + (k0 - HDIM));
    unsigned short* dst = wf + (size_t)gid * 8;
#pragma unroll
    for (int j = 0; j < 8; ++j) dst[j] = f2bf(src[j]);
}

// ---------------------------------------------------------------------------
// x fragment prep: per t, xf[t][kb][nb][lane][j]  (B-operand layout)
// ---------------------------------------------------------------------------
__global__ void __launch_bounds__(256) prep_xfrag(
    const float* __restrict__ x, unsigned short* __restrict__ xf)
{
    int gid  = blockIdx.x * 256 + threadIdx.x;   // 2,097,152
    int lane = gid & 63;
    int nb   = (gid >> 6) & 1;
    int kb   = (gid >> 7) & 31;
    int t    = gid >> 12;
    int b    = nb * 16 + (lane & 15);
    int k0   = kb * 32 + (lane >> 4) * 8;
    const float* src = x + ((size_t)(t * BATCH + b)) * HDIM + k0;
    unsigned short* dst = xf + (size_t)t * 32768 + (((kb * 2 + nb) * 64 + lane) * 8);
#pragma unroll
    for (int j = 0; j < 8; ++j) dst[j] = f2bf(src[j]);
}

// ---------------------------------------------------------------------------
// Persistent LSTM layer: 128 WGs x 256 thr (1 WG/CU = 1 wave/SIMD).
// M-SPLIT WAVES: wave v owns quadrant (mt=v>>1, nb=v&1) = 16 gate rows x 16
// batches and computes it over the FULL K=2048 (64 MFMAs, 4 indep chains).
// No cross-wave reduction, no LDS, ZERO barriers in the step loop.
//
// Sync: SENTINEL-IN-DATA: ring pre-filled 0xFF; consumers poll their own
// 32-fragment nb-half with coherent loads until no dword == -1 (every ring
// dword is written entirely by ONE 8B store -> partial-publish safe). The
// attempt that passes IS the data load.
//
// RULE-18 FIX (round-4 NaN root cause): hipcc may hoist register-only
// consumers (the sentinel check / MFMAs reading hv) PAST the inline-asm
// s_waitcnt vmcnt(0) — "memory" clobber does not order register-only ops —
// so the check could read pre-load garbage and spuriously pass.
// __builtin_amdgcn_sched_barrier(0) immediately after the waitcnt pins the
// order (nothing crosses in either direction).
//
// Slot reuse: my poll of h(t) passing proves all same-nb waves finished step
// t-1 (they are exactly the readers of my pieces), so I re-sentinel my own
// 8B pieces of slot (slot+15)&15. Ordering of the fire-and-forget stores is
// guaranteed by the NEXT step's poll vmcnt(0) (drains re-sentinel/publish
// 13+ steps before their addresses are rewritten). nb=0/nb=1 dependency
// graphs share zero ring bytes -> unbounded cross-half skew is harmless.
// Cross-layer: slots 1..14 end layer 1 sentineled; slot 15 (stale data) is
// re-sentineled by every wave's iter-0 re-sentinel, drained by iter-1 polls.
//
// VGPR budget: weights 256 + hv 128 + xv window 32 + acc 16 + misc ~ 450
// < 512 (1 wave/SIMD) — x-phase chunked by 8 fragments to keep the window.
// ---------------------------------------------------------------------------
__global__ void __launch_bounds__(256, 1) lstm_persistent(
    const unsigned short* __restrict__ xf,
    const unsigned short* __restrict__ wf,
    unsigned short* __restrict__ ring,
    const float* __restrict__ bih, const float* __restrict__ bhh,
    float* __restrict__ cbuf,
    float* __restrict__ hs,
    int slot0)
{
    const int tid  = threadIdx.x;
    const int w    = blockIdx.x;
    const int lane = tid & 63;
    const int v    = tid >> 6;
    const int mt   = v >> 1;
    const int nb   = v & 1;
    const int n    = lane & 15;
    const int p    = lane >> 4;       // 0..3: h-dim offset within the wave

    // ---- stage weights global -> REGISTERS (once per layer): 256 VGPRs ----
    short8 wAx[32], wAh[32];
    {
        const short8* wsrc = (const short8*)(wf + (size_t)w * 65536);
#pragma unroll
        for (int kb = 0; kb < 32; ++kb) {
            wAx[kb] = wsrc[(mt * 64 + kb) * 64 + lane];
            wAh[kb] = wsrc[(mt * 64 + 32 + kb) * 64 + lane];
        }
    }
    // bias for the 4 gates of this lane's (h-dim p)
    float bias4[4];
#pragma unroll
    for (int q = 0; q < 4; ++q) {
        int row = q * HDIM + w * 8 + mt * 4 + p;
        bias4[q] = bih[row] + bhh[row];
    }

    const int b = nb * 16 + n;        // batch
    const int j = w * 8 + mt * 4 + p; // global h-dim
    float creg = cbuf[b * HDIM + j];

    // publish / re-sentinel byte offset for this wave's pieces (lanes p==0)
    const int kb2   = w >> 2;
    const int lane2 = ((w & 3) << 4) | n;
    const size_t pub_off = ((size_t)((kb2 * 2 + nb) * 64 + lane2)) * 16 + (size_t)mt * 8;

    int slot = slot0;
    for (int t = 0; t < T_STEPS; ++t) {
        const unsigned short* xb = xf + (size_t)t * 32768;

        floatx4 ac0 = {0.f,0.f,0.f,0.f}, ac1 = {0.f,0.f,0.f,0.f};
        floatx4 ac2 = {0.f,0.f,0.f,0.f}, ac3 = {0.f,0.f,0.f,0.f};

        // ---- x-part MFMAs in 4 chunks of 8 fragments (32-VGPR window) ----
#pragma unroll
        for (int c = 0; c < 4; ++c) {
            short8 xv[8];
#pragma unroll
            for (int i = 0; i < 8; ++i)
                xv[i] = *(const short8*)(xb + (size_t)(((c * 8 + i) * 2 + nb) * 64 + lane) * 8);
#pragma unroll
            for (int i = 0; i < 8; i += 4) {
                ac0 = __builtin_amdgcn_mfma_f32_16x16x32_bf16(wAx[c*8+i+0], xv[i+0], ac0, 0, 0, 0);
                ac1 = __builtin_amdgcn_mfma_f32_16x16x32_bf16(wAx[c*8+i+1], xv[i+1], ac1, 0, 0, 0);
                ac2 = __builtin_amdgcn_mfma_f32_16x16x32_bf16(wAx[c*8+i+2], xv[i+2], ac2, 0, 0, 0);
                ac3 = __builtin_amdgcn_mfma_f32_16x16x32_bf16(wAx[c*8+i+3], xv[i+3], ac3, 0, 0, 0);
            }
        }

        // ---- h(t): poll own 32-fragment chunk (full K, own nb-half).
        //      The attempt that passes IS the data load. ----
        const unsigned short* rb = ring + (size_t)slot * 32768;
        short8 hv[32];
        for (;;) {
#pragma unroll
            for (int kb = 0; kb < 32; ++kb)
                hv[kb] = coh_load16(rb + (size_t)((kb * 2 + nb) * 64 + lane) * 8);
            waitcnt_vm0();
            __builtin_amdgcn_sched_barrier(0);   // rule-18: pin check AFTER drain
            int ok = 1;
#pragma unroll
            for (int kb = 0; kb < 32; ++kb) {
                intx4 q4 = __builtin_bit_cast(intx4, hv[kb]);
                ok &= (q4.x != -1) & (q4.y != -1) & (q4.z != -1) & (q4.w != -1);
            }
            if (__all(ok)) break;
            __builtin_amdgcn_s_sleep(1);
        }
        __builtin_amdgcn_sched_barrier(0);       // nothing hoists above the poll

        // ---- re-sentinel own pieces of slot (t-1)'s h (fire-and-forget;
        //      ordered vs reuse by next step's poll vmcnt(0)) ----
        if (p == 0) {
            char* sp = (char*)(ring + (size_t)((slot + RING - 1) & (RING - 1)) * 32768);
            intx2 ff = {-1, -1};
            coh_store8(sp + pub_off, ff);
        }

        // ---- h-part MFMAs (pure register chains) ----
#pragma unroll
        for (int kb = 0; kb < 32; kb += 4) {
            ac0 = __builtin_amdgcn_mfma_f32_16x16x32_bf16(wAh[kb+0], hv[kb+0], ac0, 0, 0, 0);
            ac1 = __builtin_amdgcn_mfma_f32_16x16x32_bf16(wAh[kb+1], hv[kb+1], ac1, 0, 0, 0);
            ac2 = __builtin_amdgcn_mfma_f32_16x16x32_bf16(wAh[kb+2], hv[kb+2], ac2, 0, 0, 0);
            ac3 = __builtin_amdgcn_mfma_f32_16x16x32_bf16(wAh[kb+3], hv[kb+3], ac3, 0, 0, 0);
        }
        floatx4 a = (ac0 + ac1) + (ac2 + ac3);

        // ---- in-register (q,r) transpose: lane(q,n) reg r -> lane(p,n) reg q
        float g0 = a[0], g1 = a[1], g2 = a[2], g3 = a[3];
        {
            int q0 = (lane >> 4) & 1;
            float s1 = q0 ? g0 : g1;
            float r1 = __shfl_xor(s1, 16, 64);
            if (q0) g0 = r1; else g1 = r1;
            float s2 = q0 ? g2 : g3;
            float r2 = __shfl_xor(s2, 16, 64);
            if (q0) g2 = r2; else g3 = r2;
        }
        {
            int q1 = (lane >> 5) & 1;
            float s1 = q1 ? g0 : g2;
            float r1 = __shfl_xor(s1, 32, 64);
            if (q1) g0 = r1; else g2 = r1;
            float s2 = q1 ? g1 : g3;
            float r2 = __shfl_xor(s2, 32, 64);
            if (q1) g1 = r2; else g3 = r2;
        }

        // ---- gate nonlinearities + c/h update (one (p,n) per lane) ----
        float i_ = fast_sigmoid(g0 + bias4[0]);
        float f_ = fast_sigmoid(g1 + bias4[1]);
        float g_ = fast_tanh   (g2 + bias4[2]);
        float o_ = fast_sigmoid(g3 + bias4[3]);
        creg = f_ * creg + i_ * g_;
        float hval = o_ * fast_tanh(creg);

        // ---- pack 4 h-dims into 8B on lanes p==0 and publish coherently ----
        unsigned hb   = f2bf(hval);
        float    hx   = __shfl_xor(hval, 16, 64);
        unsigned pair = hb | ((unsigned)f2bf(hx) << 16);      // (p, p^1)
        unsigned pr2  = (unsigned)__shfl_xor((int)pair, 32, 64); // (p^2, p^3)
        int slot_out = (slot + 1) & (RING - 1);
        if (p == 0) {
            char* hn = (char*)(ring + (size_t)slot_out * 32768);
            intx2 val; val.x = (int)pair; val.y = (int)pr2;
            coh_store8(hn + pub_off, val);
        }
        // hs history store (not on the critical path)
        hs[((size_t)t * BATCH + b) * HDIM + j] = hval;
        slot = slot_out;
    }
    cbuf[b * HDIM + j] = creg;
}

// ---------------------------------------------------------------------------
// Adapter (x + up(relu(down(x)))) + LayerNorm. 8 rows per WG (2048 WGs).
// NOTE: jj loop is FULLY unrolled so y[] stays in registers (partial unroll
// left a runtime base index -> y[] demoted to scratch; rule #20).
// ---------------------------------------------------------------------------
__global__ void __launch_bounds__(256) adapter_ln(
    const float* __restrict__ xin,
    const float* __restrict__ Adw, const float* __restrict__ Adb,
    const float* __restrict__ Auw, const float* __restrict__ Aub,
    const float* __restrict__ lng, const float* __restrict__ lnb,
    float* __restrict__ outf, unsigned short* __restrict__ xfout)
{
    __shared__ float xs[AROWS * 1024];     // 32 KB
    __shared__ float dbuf[AROWS * 64];     // 2 KB
    __shared__ float red2[AROWS * 32 * 2]; // 2 KB
    __shared__ float mv[AROWS * 2];
    const int tid = threadIdx.x;
    const int r0  = blockIdx.x * AROWS;

    // stage 8 rows (coalesced float4)
    {
        const float4* src4 = (const float4*)(xin + (size_t)r0 * HDIM);
        float4* xs4 = (float4*)xs;
        for (int i = tid; i < AROWS * 256; i += 256) xs4[i] = src4[i];
    }
    __syncthreads();

    const int row = tid >> 5;   // 0..7
    const int sg  = tid & 31;

    // ---- down-proj: thread computes d[row][2 a's] over full K ----
    {
        const float4* w0 = (const float4*)Adw + (size_t)(sg * 2) * 256;
        const float4* w1 = w0 + 256;
        const float4* xr = (const float4*)xs + row * 256;
        float acc0 = 0.f, acc1 = 0.f;
#pragma unroll 4
        for (int k = 0; k < 256; ++k) {
            float4 xv = xr[k];
            float4 wa = w0[k], wb = w1[k];
            acc0 += wa.x*xv.x + wa.y*xv.y + wa.z*xv.z + wa.w*xv.w;
            acc1 += wb.x*xv.x + wb.y*xv.y + wb.z*xv.z + wb.w*xv.w;
        }
        acc0 += Adb[sg * 2];
        acc1 += Adb[sg * 2 + 1];
        dbuf[row * 64 + sg * 2]     = acc0 > 0.f ? acc0 : 0.f;
        dbuf[row * 64 + sg * 2 + 1] = acc1 > 0.f ? acc1 : 0.f;
    }
    __syncthreads();

    // ---- up-proj: thread owns 32 consecutive j for its row ----
    float4 dr[16];
    {
        const float4* dv = (const float4*)(dbuf + row * 64);
#pragma unroll
        for (int q = 0; q < 16; ++q) dr[q] = dv[q];
    }
    float y[32]; float s1 = 0.f, s2 = 0.f;
#pragma unroll
    for (int jj = 0; jj < 32; ++jj) {
        int jidx = sg * 32 + jj;
        const float4* urow = (const float4*)(Auw + (size_t)jidx * DA_DIM);
        float acc = xs[row * 1024 + jidx] + Aub[jidx];
#pragma unroll
        for (int q = 0; q < 16; ++q) {
            float4 uv = urow[q];
            acc += uv.x*dr[q].x + uv.y*dr[q].y + uv.z*dr[q].z + uv.w*dr[q].w;
        }
        y[jj] = acc; s1 += acc; s2 += acc * acc;
    }
    red2[(row * 32 + sg) * 2]     = s1;
    red2[(row * 32 + sg) * 2 + 1] = s2;
    __syncthreads();
    if (sg == 0) {
        float t1 = 0.f, t2 = 0.f;
        for (int q = 0; q < 32; ++q) {
            t1 += red2[(row * 32 + q) * 2];
            t2 += red2[(row * 32 + q) * 2 + 1];
        }
        float mean = t1 * (1.f / 1024.f);
        float var  = t2 * (1.f / 1024.f) - mean * mean;
        mv[row * 2]     = mean;
        mv[row * 2 + 1] = rsqrtf(var + EPS_LN);
    }
    __syncthreads();
    const float mean = mv[row * 2], rstd = mv[row * 2 + 1];
    const int rg = r0 + row;
    // normalize
#pragma unroll
    for (int jj = 0; jj < 32; ++jj) {
        int jidx = sg * 32 + jj;
        y[jj] = (y[jj] - mean) * rstd * lng[jidx] + lnb[jidx];
    }
    if (outf) {
        float4* o4 = (float4*)(outf + (size_t)rg * HDIM + sg * 32);
#pragma unroll
        for (int q = 0; q < 8; ++q) {
            float4 ov = { y[q*4], y[q*4+1], y[q*4+2], y[q*4+3] };
            o4[q] = ov;
        }
    }
    if (xfout) {
        int t = rg >> 5, b = rg & 31;
        int nb = b >> 4;
        unsigned short* base = xfout + (size_t)t * 32768;
#pragma unroll
        for (int g = 0; g < 4; ++g) {
            int lane2 = (g << 4) | (b & 15);
            unsigned short tmp[8];
#pragma unroll
            for (int e = 0; e < 8; ++e) tmp[e] = f2bf(y[g * 8 + e]);
            *(short8*)(base + (size_t)((sg * 2 + nb) * 64 + lane2) * 8) = *(short8*)tmp;
        }
    }
}

extern "C" void kernel_launch(void* const* d_in, const int* in_sizes, int n_in,
                              void* d_out, int out_size, void* d_ws, size_t ws_size,
                              hipStream_t stream)
{
    const float* x   = (const float*)d_in[0];
    const float* Wih = (const float*)d_in[1];
    const float* Whh = (const float*)d_in[2];
    const float* bih = (const float*)d_in[3];
    const float* bhh = (const float*)d_in[4];
    const float* Adw = (const float*)d_in[5];
    const float* Adb = (const float*)d_in[6];
    const float* Auw = (const float*)d_in[7];
    const float* Aub = (const float*)d_in[8];
    const float* lng = (const float*)d_in[9];
    const float* lnb = (const float*)d_in[10];
    float* out = (float*)d_out;

    // workspace carve (~52 MB)
    char* ws = (char*)d_ws;
    unsigned short* wfb  = (unsigned short*)ws; ws += (size_t)GATE4 * 2048 * 2;      // 16.78 MB
    unsigned short* xfb  = (unsigned short*)ws; ws += (size_t)T_STEPS * 32768 * 2;   // 33.55 MB
    unsigned short* ring = (unsigned short*)ws; ws += (size_t)RING * 32768 * 2;      // 1 MB
    float*    cbuf  = (float*)ws;    ws += (size_t)BATCH * HDIM * 4;                 // 128 KB
    float* hs = out;   // alias hs onto d_out x-region (adapter is in-place safe)

    hipMemsetAsync(cbuf, 0, (size_t)BATCH * HDIM * 4, stream);
    // slot 0 = h0 = zeros (valid data); slots 1..15 = 0xFF sentinel
    hipMemsetAsync(ring, 0, 65536, stream);
    hipMemsetAsync((char*)ring + 65536, 0xFF, (size_t)(RING - 1) * 65536, stream);

    prep_xfrag<<<8192, 256, 0, stream>>>(x, xfb);

    for (int l = 0; l < 2; ++l) {
        prep_wfrag<<<4096, 256, 0, stream>>>(Wih + (size_t)l * GATE4 * HDIM,
                                             Whh + (size_t)l * GATE4 * HDIM, wfb);
        // global step g = l*512 + t; slot = g & 15; 512 % 16 == 0 so slot0 = 0
        // both layers; sentinel protocol is continuous across the boundary and
        // layer 2's h0 = hT of layer 1 = exactly what sits in slot 0.
        lstm_persistent<<<PWG, 256, 0, stream>>>(xfb, wfb, ring,
                                                 bih + (size_t)l * GATE4,
                                                 bhh + (size_t)l * GATE4,
                                                 cbuf, hs, 0);

        const float* adw = Adw + (size_t)l * DA_DIM * HDIM;
        const float* adb = Adb + (size_t)l * DA_DIM;
        const float* auw = Auw + (size_t)l * HDIM * DA_DIM;
        const float* aub = Aub + (size_t)l * HDIM;
        const float* lg  = lng + (size_t)l * HDIM;
        const float* lb  = lnb + (size_t)l * HDIM;
        if (l == 0) {
            adapter_ln<<<T_STEPS * BATCH / AROWS, 256, 0, stream>>>(
                hs, adw, adb, auw, aub, lg, lb, nullptr, xfb);
        } else {
            hipMemcpyAsync(out + 16777216, hs + (size_t)511 * BATCH * HDIM,
                           (size_t)BATCH * HDIM * 4, hipMemcpyDeviceToDevice, stream);
            hipMemcpyAsync(out + 16777216 + 32768, cbuf,
                           (size_t)BATCH * HDIM * 4, hipMemcpyDeviceToDevice, stream);
            adapter_ln<<<T_STEPS * BATCH / AROWS, 256, 0, stream>>>(
                hs, adw, adb, auw, aub, lg, lb, out, nullptr);
        }
    }
}

// Round 6
// 3284.220 us; speedup vs baseline: 1.8876x; 1.8876x over previous
//
#include <hip/hip_runtime.h>
#include <hip/hip_bf16.h>

typedef __attribute__((ext_vector_type(8))) short short8;
typedef __attribute__((ext_vector_type(4))) float floatx4;
typedef __attribute__((ext_vector_type(4))) int intx4;
typedef __attribute__((ext_vector_type(2))) int intx2;

#define T_STEPS 512
#define BATCH   32
#define HDIM    1024
#define GATE4   4096
#define DA_DIM  64
#define PWG     128
#define RING    16
#define EPS_LN  1e-5f

// LDS bank-conflict swizzles (lstm reduction): flip addr bit4 with row parity
#define PSWZ(row, n) ((((row) * 16 + (n))) ^ ((((row) >> 2) & 1) << 4))
#define GSWZ(row, col) ((row) * 32 + (((col) ^ (((row) & 1) << 4))))

// round-to-nearest-even fp32 -> bf16. Finite input never yields 0xFFFF, so
// 0xFFFFFFFF dwords are a safe "not yet written" sentinel.
__device__ __forceinline__ unsigned short f2bf(float f) {
    unsigned u = __float_as_uint(f);
    unsigned r = (u + 0x7FFFu + ((u >> 16) & 1u)) >> 16;
    return (unsigned short)r;
}
__device__ __forceinline__ float fast_sigmoid(float x) {
    return __builtin_amdgcn_rcpf(1.f + __expf(-x));
}
__device__ __forceinline__ float fast_tanh(float x) {
    return 1.f - 2.f * __builtin_amdgcn_rcpf(1.f + __expf(2.f * x));
}
__device__ __forceinline__ void coh_store16(void* p, intx4 v) {
    asm volatile("global_store_dwordx4 %0, %1, off sc0 sc1" :: "v"(p), "v"(v) : "memory");
}
__device__ __forceinline__ short8 coh_load16(const void* p) {
    short8 v;
    asm volatile("global_load_dwordx4 %0, %1, off sc0 sc1" : "=v"(v) : "v"(p) : "memory");
    return v;
}
__device__ __forceinline__ void waitcnt_vm0() {
    asm volatile("s_waitcnt vmcnt(0)" ::: "memory");
}

// ---------------------------------------------------------------------------
// W fragment prep: wf[w][mt][kb][lane][j]  (A-operand layout, K=[x;h], 2048)
// ---------------------------------------------------------------------------
__global__ void __launch_bounds__(256) prep_wfrag(
    const float* __restrict__ Wih, const float* __restrict__ Whh,
    unsigned short* __restrict__ wf)
{
    int gid  = blockIdx.x * 256 + threadIdx.x;   // 1,048,576
    int lane = gid & 63;
    int kb   = (gid >> 6) & 63;
    int mt   = (gid >> 12) & 1;
    int w    = gid >> 13;                        // 0..127
    int m    = lane & 15;
    int row  = (m >> 2) * HDIM + w * 8 + mt * 4 + (m & 3);
    int k0   = kb * 32 + (lane >> 4) * 8;
    const float* src = (k0 < HDIM) ? (Wih + (size_t)row * HDIM + k0)
                                   : (Whh + (size_t)row * HDIM + (k0 - HDIM));
    unsigned short* dst = wf + (size_t)gid * 8;
#pragma unroll
    for (int j = 0; j < 8; ++j) dst[j] = f2bf(src[j]);
}

// ---------------------------------------------------------------------------
// x fragment prep: per t, xf[t][kb][nb][lane][j]  (B-operand layout)
// ---------------------------------------------------------------------------
__global__ void __launch_bounds__(256) prep_xfrag(
    const float* __restrict__ x, unsigned short* __restrict__ xf)
{
    int gid  = blockIdx.x * 256 + threadIdx.x;   // 2,097,152
    int lane = gid & 63;
    int nb   = (gid >> 6) & 1;
    int kb   = (gid >> 7) & 31;
    int t    = gid >> 12;
    int b    = nb * 16 + (lane & 15);
    int k0   = kb * 32 + (lane >> 4) * 8;
    const float* src = x + ((size_t)(t * BATCH + b)) * HDIM + k0;
    unsigned short* dst = xf + (size_t)t * 32768 + (((kb * 2 + nb) * 64 + lane) * 8);
#pragma unroll
    for (int j = 0; j < 8; ++j) dst[j] = f2bf(src[j]);
}

// ---------------------------------------------------------------------------
// Adapter weight fragment prep (A-operand layouts):
//  adfrag[Mt(4)][kb(32)][lane][8]  from Adw[64][1024]   (rows=adim, K=h)
//  aufrag[Mt(64)][kf(2)][lane][8]  from Auw[1024][64]   (rows=j,    K=adim)
// ---------------------------------------------------------------------------
__global__ void __launch_bounds__(256) prep_afrag(
    const float* __restrict__ Adw, const float* __restrict__ Auw,
    unsigned short* __restrict__ adfrag, unsigned short* __restrict__ aufrag)
{
    int gid  = blockIdx.x * 256 + threadIdx.x;   // 16384
    int lane = gid & 63;
    int fi   = (gid >> 6) & 127;
    int half = gid >> 13;
    int m = lane & 15, q = lane >> 4;
    const float* src;
    unsigned short* dst;
    if (half == 0) {
        int Mt = fi >> 5, kb = fi & 31;
        src = Adw + (size_t)(Mt * 16 + m) * HDIM + (kb * 32 + q * 8);
        dst = adfrag + (size_t)(fi * 64 + lane) * 8;
    } else {
        int Mt = fi >> 1, kf = fi & 1;
        src = Auw + (size_t)(Mt * 16 + m) * DA_DIM + (kf * 32 + q * 8);
        dst = aufrag + (size_t)(fi * 64 + lane) * 8;
    }
#pragma unroll
    for (int j = 0; j < 8; ++j) dst[j] = f2bf(src[j]);
}

// ---------------------------------------------------------------------------
// Persistent LSTM layer (round-2 structure, 1537us proven): 128 WGs x 256 thr
// (1 WG/CU). Wave v owns K-chunk; weights REGISTER-resident (128 VGPR/wave);
// cross-wave K-reduction via swizzled LDS; wave 0 publishes, wave 3
// re-sentinels. Sentinel-in-data sync (0xFF prefill; poll own 16KB chunk).
// RULE-18: sched_barrier(0) after the poll's vmcnt(0) so the register-only
// sentinel check cannot be hoisted past the drain (round-4 NaN root cause).
// NEW: publishing lanes also mirror h(t) fragments to hfrag[t] with a plain
// store (off critical path) -- feeds the MFMA adapter's B-operand.
// ---------------------------------------------------------------------------
__global__ void __launch_bounds__(256, 1) lstm_persistent(
    const unsigned short* __restrict__ xf,
    const unsigned short* __restrict__ wf,
    unsigned short* __restrict__ ring,
    unsigned short* __restrict__ hfrag,
    const float* __restrict__ bih, const float* __restrict__ bhh,
    float* __restrict__ cbuf,
    float* __restrict__ hs,
    int slot0)
{
    __shared__ float part[16 * 256];      // 16 KB (PSWZ)
    __shared__ float gates[2 * 16 * 32];  // 4 KB (GSWZ)
    __shared__ float bias_s[32];
    __shared__ intx4 hstage4[32];

    const int tid  = threadIdx.x;
    const int w    = blockIdx.x;
    const int lane = tid & 63;
    const int v    = tid >> 6;

    // ---- stage weights global -> REGISTERS (once per layer) ----
    short8 wx0[8], wx1[8], wh0[8], wh1[8];
    {
        const short8* wsrc = (const short8*)(wf + (size_t)w * 65536);
#pragma unroll
        for (int i = 0; i < 8; ++i) {
            int kb = v * 8 + i;
            wx0[i] = wsrc[(0 * 64 +      kb) * 64 + lane];
            wx1[i] = wsrc[(1 * 64 +      kb) * 64 + lane];
            wh0[i] = wsrc[(0 * 64 + 32 + kb) * 64 + lane];
            wh1[i] = wsrc[(1 * 64 + 32 + kb) * 64 + lane];
        }
    }
    if (tid < 32) {
        int mt = tid >> 4, m = tid & 15;
        int row = (m >> 2) * HDIM + w * 8 + mt * 4 + (m & 3);
        bias_s[tid] = bih[row] + bhh[row];
    }
    const int hd = tid >> 5;
    const int bb = tid & 31;
    const int j  = w * 8 + hd;
    float creg = cbuf[bb * HDIM + j];
    __syncthreads();

    int slot = slot0;
    for (int t = 0; t < T_STEPS; ++t) {
        const unsigned short* xb = xf + (size_t)t * 32768;

        short8 xv[8][2];
#pragma unroll
        for (int i = 0; i < 8; ++i) {
            const unsigned short* xp = xb + (size_t)((v * 8 + i) * 128 + lane) * 8;
            xv[i][0] = *(const short8*)xp;
            xv[i][1] = *(const short8*)(xp + 512);
        }

        floatx4 a00 = {0.f,0.f,0.f,0.f}, a01 = {0.f,0.f,0.f,0.f};
        floatx4 a10 = {0.f,0.f,0.f,0.f}, a11 = {0.f,0.f,0.f,0.f};

        // x-part MFMAs (all-register) -- overlaps other WGs' publish flight
#pragma unroll
        for (int i = 0; i < 8; ++i) {
            a00 = __builtin_amdgcn_mfma_f32_16x16x32_bf16(wx0[i], xv[i][0], a00, 0, 0, 0);
            a01 = __builtin_amdgcn_mfma_f32_16x16x32_bf16(wx0[i], xv[i][1], a01, 0, 0, 0);
            a10 = __builtin_amdgcn_mfma_f32_16x16x32_bf16(wx1[i], xv[i][0], a10, 0, 0, 0);
            a11 = __builtin_amdgcn_mfma_f32_16x16x32_bf16(wx1[i], xv[i][1], a11, 0, 0, 0);
        }

        // h(t-1): per-wave sentinel poll on own 16 KB K-chunk
        const unsigned short* rb = ring + (size_t)slot * 32768;
        short8 hv[8][2];
        {
            const unsigned short* hp0 = rb + (size_t)(v * 8 * 128 + lane) * 8;
            for (;;) {
#pragma unroll
                for (int i = 0; i < 8; ++i) {
                    const unsigned short* hp = hp0 + (size_t)i * 1024;
                    hv[i][0] = coh_load16(hp);
                    hv[i][1] = coh_load16(hp + 512);
                }
                waitcnt_vm0();
                __builtin_amdgcn_sched_barrier(0);   // rule-18: check AFTER drain
                int ok = 1;
#pragma unroll
                for (int i = 0; i < 8; ++i)
#pragma unroll
                    for (int u = 0; u < 2; ++u) {
                        intx4 q4 = __builtin_bit_cast(intx4, hv[i][u]);
                        ok &= (q4.x != -1) & (q4.y != -1) & (q4.z != -1) & (q4.w != -1);
                    }
                if (__all(ok)) break;
                __builtin_amdgcn_s_sleep(1);
            }
        }
        __builtin_amdgcn_sched_barrier(0);           // nothing hoists above poll

        // h-part MFMAs (pure register chain)
#pragma unroll
        for (int i = 0; i < 8; ++i) {
            a00 = __builtin_amdgcn_mfma_f32_16x16x32_bf16(wh0[i], hv[i][0], a00, 0, 0, 0);
            a01 = __builtin_amdgcn_mfma_f32_16x16x32_bf16(wh0[i], hv[i][1], a01, 0, 0, 0);
            a10 = __builtin_amdgcn_mfma_f32_16x16x32_bf16(wh1[i], hv[i][0], a10, 0, 0, 0);
            a11 = __builtin_amdgcn_mfma_f32_16x16x32_bf16(wh1[i], hv[i][1], a11, 0, 0, 0);
        }

        // cross-wave K reduction via LDS (swizzled)
        {
            int n = lane & 15, q = lane >> 4;
#pragma unroll
            for (int r = 0; r < 4; ++r) {
                int row = q * 4 + r;
                part[(v * 4 + 0) * 256 + PSWZ(row, n)] = a00[r];
                part[(v * 4 + 1) * 256 + PSWZ(row, n)] = a01[r];
                part[(v * 4 + 2) * 256 + PSWZ(row, n)] = a10[r];
                part[(v * 4 + 3) * 256 + PSWZ(row, n)] = a11[r];
            }
        }
        __syncthreads();
        // re-sentinel slot of h(t-2) (wave 3; proof of safety: h(t-1) poll passed)
        if (tid >= 192 && tid < 224) {
            int s32 = tid - 192;
            unsigned short* sp = ring + (size_t)((slot + RING - 1) & (RING - 1)) * 32768;
            int kb2   = w >> 2;
            int lane2 = ((w & 3) << 4) | (s32 & 15);
            intx4 ff = {-1, -1, -1, -1};
            coh_store16(sp + (size_t)((kb2 * 2 + (s32 >> 4)) * 64 + lane2) * 8, ff);
        }
        {
            int m = tid >> 4, n = tid & 15;
#pragma unroll
            for (int mt = 0; mt < 2; ++mt)
#pragma unroll
                for (int nb = 0; nb < 2; ++nb) {
                    int c = mt * 2 + nb;
                    float g = part[(0 * 4 + c) * 256 + PSWZ(m, n)]
                            + part[(1 * 4 + c) * 256 + PSWZ(m, n)]
                            + part[(2 * 4 + c) * 256 + PSWZ(m, n)]
                            + part[(3 * 4 + c) * 256 + PSWZ(m, n)];
                    gates[GSWZ(mt * 16 + m, nb * 16 + n)] = g + bias_s[mt * 16 + m];
                }
        }
        __syncthreads();

        // gate nonlinearities + c/h update
        float hval;
        {
            int r3 = hd & 3, mt = hd >> 2;
            float gi = gates[GSWZ(mt * 16 +  0 + r3, bb)];
            float gf = gates[GSWZ(mt * 16 +  4 + r3, bb)];
            float gg = gates[GSWZ(mt * 16 +  8 + r3, bb)];
            float go = gates[GSWZ(mt * 16 + 12 + r3, bb)];
            float i_ = fast_sigmoid(gi);
            float f_ = fast_sigmoid(gf);
            float g_ = fast_tanh(gg);
            float o_ = fast_sigmoid(go);
            creg = f_ * creg + i_ * g_;
            hval = o_ * fast_tanh(creg);
            ((unsigned short*)&hstage4[bb])[hd] = f2bf(hval);
        }
        __syncthreads();

        // publish h(t): coherent to ring (critical) + plain mirror to hfrag[t]
        int slot_out = (slot + 1) & (RING - 1);
        if (tid < 32) {
            int kb2   = w >> 2;
            int lane2 = ((w & 3) << 4) | (tid & 15);
            size_t off = (size_t)((kb2 * 2 + (tid >> 4)) * 64 + lane2) * 8;
            intx4 hval4 = hstage4[tid];
            coh_store16(ring + (size_t)slot_out * 32768 + off, hval4);
            *(intx4*)(hfrag + (size_t)t * 32768 + off) = hval4;
        }
        hs[((size_t)t * BATCH + bb) * HDIM + j] = hval;
        slot = slot_out;
    }
    cbuf[bb * HDIM + j] = creg;
}

// ---------------------------------------------------------------------------
// MFMA adapter + LayerNorm. One WG per t (512 WGs, 2/CU).
//   D = relu(Adw . X + Adb)   [64 x 32]   (K=1024, B-frags from hfrag[t])
//   Y = X + Auw . D + Aub     [1024 x 32] (K=64,  B-frags via dlds)
//   out = LN(Y)
// Replaces the VMEM-issue-bound VALU adapter (~541M vmem instrs ~ 1.8 ms).
// ---------------------------------------------------------------------------
__global__ void __launch_bounds__(256, 2) adapter_mfma(
    const unsigned short* __restrict__ hfrag,
    const float* __restrict__ hs,
    const unsigned short* __restrict__ adfrag,
    const unsigned short* __restrict__ aufrag,
    const float* __restrict__ Adb, const float* __restrict__ Aub,
    const float* __restrict__ lng, const float* __restrict__ lnb,
    float* __restrict__ outf, unsigned short* __restrict__ xfout)
{
    __shared__ unsigned short dlds[32][72];    // [b][adim] bf16, 16B-aligned rows
    __shared__ unsigned short ylds[32][1032];  // [b][j] bf16 (xfout path only)
    __shared__ float red[4][2][16][2];
    __shared__ float mv[32][2];

    const int tid  = threadIdx.x;
    const int lane = tid & 63;
    const int v    = tid >> 6;
    const int t    = blockIdx.x;
    const int n    = lane & 15;
    const int q    = lane >> 4;

    // ---- down-proj: wave v owns adims v*16..v*16+15 ----
    const unsigned short* hb = hfrag + (size_t)t * 32768;
    floatx4 d0 = {0.f,0.f,0.f,0.f}, d1 = {0.f,0.f,0.f,0.f};
#pragma unroll 8
    for (int kb = 0; kb < 32; ++kb) {
        short8 a  = *(const short8*)(adfrag + (size_t)((v * 32 + kb) * 64 + lane) * 8);
        short8 b0 = *(const short8*)(hb + (size_t)((kb * 2 + 0) * 64 + lane) * 8);
        short8 b1 = *(const short8*)(hb + (size_t)((kb * 2 + 1) * 64 + lane) * 8);
        d0 = __builtin_amdgcn_mfma_f32_16x16x32_bf16(a, b0, d0, 0, 0, 0);
        d1 = __builtin_amdgcn_mfma_f32_16x16x32_bf16(a, b1, d1, 0, 0, 0);
    }
    {
        int a0 = v * 16 + q * 4;
        unsigned short p0[4], p1[4];
#pragma unroll
        for (int r = 0; r < 4; ++r) {
            float bi = Adb[a0 + r];
            float x0 = d0[r] + bi, x1 = d1[r] + bi;
            p0[r] = f2bf(x0 > 0.f ? x0 : 0.f);
            p1[r] = f2bf(x1 > 0.f ? x1 : 0.f);
        }
        intx2 w0, w1;
        w0.x = (int)(p0[0] | ((unsigned)p0[1] << 16));
        w0.y = (int)(p0[2] | ((unsigned)p0[3] << 16));
        w1.x = (int)(p1[0] | ((unsigned)p1[1] << 16));
        w1.y = (int)(p1[2] | ((unsigned)p1[3] << 16));
        *(intx2*)&dlds[n][a0]      = w0;
        *(intx2*)&dlds[16 + n][a0] = w1;
    }
    __syncthreads();

    // ---- up-proj: wave v owns j-rows v*256..v*256+255 (16 Mtiles) ----
    short8 bfr[2][2];
#pragma unroll
    for (int kf = 0; kf < 2; ++kf)
#pragma unroll
        for (int nt = 0; nt < 2; ++nt)
            bfr[kf][nt] = *(const short8*)&dlds[nt * 16 + n][kf * 32 + q * 8];

    floatx4 acc[16][2];
#pragma unroll
    for (int mt = 0; mt < 16; ++mt) {
        acc[mt][0] = (floatx4){0.f,0.f,0.f,0.f};
        acc[mt][1] = (floatx4){0.f,0.f,0.f,0.f};
    }
#pragma unroll
    for (int mt = 0; mt < 16; ++mt) {
        int Mt = v * 16 + mt;
        short8 au0 = *(const short8*)(aufrag + (size_t)((Mt * 2 + 0) * 64 + lane) * 8);
        short8 au1 = *(const short8*)(aufrag + (size_t)((Mt * 2 + 1) * 64 + lane) * 8);
        acc[mt][0] = __builtin_amdgcn_mfma_f32_16x16x32_bf16(au0, bfr[0][0], acc[mt][0], 0, 0, 0);
        acc[mt][0] = __builtin_amdgcn_mfma_f32_16x16x32_bf16(au1, bfr[1][0], acc[mt][0], 0, 0, 0);
        acc[mt][1] = __builtin_amdgcn_mfma_f32_16x16x32_bf16(au0, bfr[0][1], acc[mt][1], 0, 0, 0);
        acc[mt][1] = __builtin_amdgcn_mfma_f32_16x16x32_bf16(au1, bfr[1][1], acc[mt][1], 0, 0, 0);
    }

    // ---- epilogue: + x + Aub, LN stats ----
    float s1[2] = {0.f, 0.f}, s2[2] = {0.f, 0.f};
#pragma unroll
    for (int mt = 0; mt < 16; ++mt) {
        int j0 = (v * 16 + mt) * 16 + q * 4;
        floatx4 u = *(const floatx4*)(Aub + j0);
#pragma unroll
        for (int nt = 0; nt < 2; ++nt) {
            int b = nt * 16 + n;
            floatx4 r = *(const floatx4*)(hs + ((size_t)(t * BATCH + b)) * HDIM + j0);
#pragma unroll
            for (int e = 0; e < 4; ++e) {
                float y = acc[mt][nt][e] + r[e] + u[e];
                acc[mt][nt][e] = y;
                s1[nt] += y; s2[nt] += y * y;
            }
        }
    }
#pragma unroll
    for (int nt = 0; nt < 2; ++nt) {
        s1[nt] += __shfl_xor(s1[nt], 16, 64); s1[nt] += __shfl_xor(s1[nt], 32, 64);
        s2[nt] += __shfl_xor(s2[nt], 16, 64); s2[nt] += __shfl_xor(s2[nt], 32, 64);
    }
    if (q == 0) {
        red[v][0][n][0] = s1[0]; red[v][0][n][1] = s2[0];
        red[v][1][n][0] = s1[1]; red[v][1][n][1] = s2[1];
    }
    __syncthreads();
    if (tid < 32) {
        int ntt = tid >> 4, nn = tid & 15;
        float t1 = 0.f, t2 = 0.f;
#pragma unroll
        for (int vv = 0; vv < 4; ++vv) { t1 += red[vv][ntt][nn][0]; t2 += red[vv][ntt][nn][1]; }
        float mean = t1 * (1.f / 1024.f);
        float var  = t2 * (1.f / 1024.f) - mean * mean;
        mv[tid][0] = mean;
        mv[tid][1] = rsqrtf(var + EPS_LN);
    }
    __syncthreads();
    float mean_[2], rstd_[2];
#pragma unroll
    for (int nt = 0; nt < 2; ++nt) { mean_[nt] = mv[nt * 16 + n][0]; rstd_[nt] = mv[nt * 16 + n][1]; }

    // ---- normalize + outputs ----
#pragma unroll
    for (int mt = 0; mt < 16; ++mt) {
        int j0 = (v * 16 + mt) * 16 + q * 4;
        floatx4 g = *(const floatx4*)(lng + j0);
        floatx4 bb4 = *(const floatx4*)(lnb + j0);
#pragma unroll
        for (int nt = 0; nt < 2; ++nt)
#pragma unroll
            for (int e = 0; e < 4; ++e)
                acc[mt][nt][e] = (acc[mt][nt][e] - mean_[nt]) * rstd_[nt] * g[e] + bb4[e];
    }
    if (outf) {
#pragma unroll
        for (int mt = 0; mt < 16; ++mt) {
            int j0 = (v * 16 + mt) * 16 + q * 4;
#pragma unroll
            for (int nt = 0; nt < 2; ++nt) {
                int b = nt * 16 + n;
                *(floatx4*)(outf + ((size_t)(t * BATCH + b)) * HDIM + j0) = acc[mt][nt];
            }
        }
    }
    if (xfout) {
#pragma unroll
        for (int mt = 0; mt < 16; ++mt) {
            int j0 = (v * 16 + mt) * 16 + q * 4;
#pragma unroll
            for (int nt = 0; nt < 2; ++nt) {
                int b = nt * 16 + n;
                intx2 pk;
                pk.x = (int)(f2bf(acc[mt][nt][0]) | ((unsigned)f2bf(acc[mt][nt][1]) << 16));
                pk.y = (int)(f2bf(acc[mt][nt][2]) | ((unsigned)f2bf(acc[mt][nt][3]) << 16));
                *(intx2*)&ylds[b][j0] = pk;
            }
        }
        __syncthreads();
#pragma unroll
        for (int i = 0; i < 16; ++i) {
            int f = v * 16 + i;
            int kb = f >> 1, nbb = f & 1;
            short8 yv = *(const short8*)&ylds[nbb * 16 + n][kb * 32 + q * 8];
            *(short8*)(xfout + (size_t)t * 32768 + (size_t)(f * 64 + lane) * 8) = yv;
        }
    }
}

extern "C" void kernel_launch(void* const* d_in, const int* in_sizes, int n_in,
                              void* d_out, int out_size, void* d_ws, size_t ws_size,
                              hipStream_t stream)
{
    const float* x   = (const float*)d_in[0];
    const float* Wih = (const float*)d_in[1];
    const float* Whh = (const float*)d_in[2];
    const float* bih = (const float*)d_in[3];
    const float* bhh = (const float*)d_in[4];
    const float* Adw = (const float*)d_in[5];
    const float* Adb = (const float*)d_in[6];
    const float* Auw = (const float*)d_in[7];
    const float* Aub = (const float*)d_in[8];
    const float* lng = (const float*)d_in[9];
    const float* lnb = (const float*)d_in[10];
    float* out = (float*)d_out;

    // workspace carve (~85.3 MB)
    char* ws = (char*)d_ws;
    unsigned short* wfb    = (unsigned short*)ws; ws += (size_t)GATE4 * 2048 * 2;    // 16.78 MB
    unsigned short* xfb    = (unsigned short*)ws; ws += (size_t)T_STEPS * 32768 * 2; // 33.55 MB
    unsigned short* hfrag  = (unsigned short*)ws; ws += (size_t)T_STEPS * 32768 * 2; // 33.55 MB
    unsigned short* ring   = (unsigned short*)ws; ws += (size_t)RING * 32768 * 2;    // 1.05 MB
    unsigned short* adfrag = (unsigned short*)ws; ws += (size_t)128 * 64 * 8 * 2;    // 128 KB
    unsigned short* aufrag = (unsigned short*)ws; ws += (size_t)128 * 64 * 8 * 2;    // 128 KB
    float* cbuf = (float*)ws; ws += (size_t)BATCH * HDIM * 4;                        // 128 KB
    float* hs = out;   // alias hs onto d_out x-region (adapter in-place safe)

    hipMemsetAsync(cbuf, 0, (size_t)BATCH * HDIM * 4, stream);
    // ring slot 0 = h0 = zeros (valid); slots 1..15 = 0xFF sentinel
    hipMemsetAsync(ring, 0, 65536, stream);
    hipMemsetAsync((char*)ring + 65536, 0xFF, (size_t)(RING - 1) * 65536, stream);

    prep_xfrag<<<8192, 256, 0, stream>>>(x, xfb);

    for (int l = 0; l < 2; ++l) {
        prep_wfrag<<<4096, 256, 0, stream>>>(Wih + (size_t)l * GATE4 * HDIM,
                                             Whh + (size_t)l * GATE4 * HDIM, wfb);
        prep_afrag<<<64, 256, 0, stream>>>(Adw + (size_t)l * DA_DIM * HDIM,
                                           Auw + (size_t)l * HDIM * DA_DIM,
                                           adfrag, aufrag);
        // 512 % 16 == 0 -> slot0 = 0 both layers; sentinel protocol continuous;
        // layer 2's h0 = hT of layer 1 = exactly what sits in slot 0.
        lstm_persistent<<<PWG, 256, 0, stream>>>(xfb, wfb, ring, hfrag,
                                                 bih + (size_t)l * GATE4,
                                                 bhh + (size_t)l * GATE4,
                                                 cbuf, hs, 0);

        const float* adb = Adb + (size_t)l * DA_DIM;
        const float* aub = Aub + (size_t)l * HDIM;
        const float* lg  = lng + (size_t)l * HDIM;
        const float* lb  = lnb + (size_t)l * HDIM;
        if (l == 0) {
            adapter_mfma<<<T_STEPS, 256, 0, stream>>>(
                hfrag, hs, adfrag, aufrag, adb, aub, lg, lb, nullptr, xfb);
        } else {
            hipMemcpyAsync(out + 16777216, hs + (size_t)511 * BATCH * HDIM,
                           (size_t)BATCH * HDIM * 4, hipMemcpyDeviceToDevice, stream);
            hipMemcpyAsync(out + 16777216 + 32768, cbuf,
                           (size_t)BATCH * HDIM * 4, hipMemcpyDeviceToDevice, stream);
            adapter_mfma<<<T_STEPS, 256, 0, stream>>>(
                hfrag, hs, adfrag, aufrag, adb, aub, lg, lb, out, nullptr);
        }
    }
}